// Round 10
// baseline (180.383 us; speedup 1.0000x reference)
//
#include <hip/hip_runtime.h>
#include <hip/hip_bf16.h>
#include <math.h>

#define NP 10
#define NE 45
#define TS 16                      // timesteps per block
#define EPB (TS * NE)              // 720 edges per block
#define BLOCK 256
#define NCHUNK ((EPB + 63) / 64)   // 12 chunks of 64 edge-slots

// workspace layout (ints): [0 .. 9*64*4) = 9 x 64 int4 weight frags,
// then einv (NP floats), mpair (NE ints), stab (NP*9 ints),
// then (16B-aligned) tanh table: 4096 ushorts (8 KB).
#define WS_EINV  (9 * 64 * 4)
#define WS_MPAIR (WS_EINV + NP)
#define WS_STAB  (WS_MPAIR + NE)
#define WS_TAB   2452              // >= WS_STAB+NP*9 (=2449), 16B-aligned

typedef __attribute__((ext_vector_type(8)))  short short8;   // 8 bf16 MFMA frag
typedef __attribute__((ext_vector_type(16))) float f32x16;   // 32x32 MFMA acc
typedef __attribute__((ext_vector_type(2)))  float f32x2;

#define C2LOG2E 2.885390081777927f   // 2*log2(e), folded into W1/W2 (+biases)
#define PI_F    3.14159265358979f
#define PIO2_F  1.57079632679490f

#define MFMA32(a, b, c) __builtin_amdgcn_mfma_f32_32x32x16_bf16(a, b, c, 0, 0, 0)

__device__ __forceinline__ float rcp_fast(float x) { return __builtin_amdgcn_rcpf(x); }

// Single-instruction bf16x2 pack (RNE). gfx950 has v_cvt_pk_bf16_f32 but no
// builtin (learn_hip m240). src0 -> low 16, src1 -> high 16.
__device__ __forceinline__ int cvt_pk_bf16(float lo, float hi) {
    int r;
    asm("v_cvt_pk_bf16_f32 %0, %1, %2" : "=v"(r) : "v"(lo), "v"(hi));
    return r;
}

// r10: TABLE tanh. r9 cycle budget: tanh = ~1920 of ~2250 VALU-busy cy/chunk,
// dominated by exp2/rcp at the measured ~16cy/wave64 trans rate. A 4096-entry
// bf16 table over s in [-16,16] (s = 2log2e*x preactivation; step 0.0027 in x
// -> error <= 0.00135 < the 0.002 bf16 rounding already applied) moves tanh
// from the saturated VALU pipe to the near-idle LDS pipe: per pair 2 fma +
// 2 med3 + 2 cvt + pack (~18 VALU cy) + 2 ds_read_u16 (LDS pipe, TLP-hidden).
// Index: i = floor(s*128 + 2048.5), clamped [0,4095]; entry i = bf16(tanh(
// (i-2048)*ln2/256)). Saturation: |s|>16 -> x>5.5 -> tanh==1.0 in bf16.
__device__ __forceinline__ int tanh_pair_tab(const unsigned short* tt,
                                             float s0, float s1) {
    float i0 = fminf(4095.0f, fmaxf(0.0f, fmaf(s0, 128.0f, 2048.5f)));
    float i1 = fminf(4095.0f, fmaxf(0.0f, fmaf(s1, 128.0f, 2048.5f)));
    unsigned v0 = tt[(unsigned)i0];
    unsigned v1 = tt[(unsigned)i1];
    return (int)(v0 | (v1 << 16));
}

__device__ __forceinline__ short bf16_rne(float f) {
    unsigned int u = __float_as_uint(f);
    return (short)((u + 0x7fffu + ((u >> 16) & 1u)) >> 16);
}
__device__ __forceinline__ int bf16pk2(float a, float b) {
    return cvt_pk_bf16(a, b);
}
__device__ __forceinline__ int bperm_i(int idx_bytes, int v) {
    return __builtin_amdgcn_ds_bpermute(idx_bytes, v);
}

// bf16-accuracy branch-free acos (A&S 4.4.45). Arg of sqrt is >=0 by
// construction; raw v_sqrt_f32 (avoids IEEE-correct fixup sequence).
__device__ __forceinline__ float acos_fast(float w) {
    float a = fabsf(w);
    float s = __builtin_amdgcn_sqrtf(1.0f - a);
    float p = fmaf(a, fmaf(a, fmaf(a, -0.0187293f, 0.0742610f), -0.2121144f), 1.5707288f);
    float v = s * p;
    return (w >= 0.0f) ? v : PI_F - v;
}
// bf16-accuracy branch-free atan2 (A&S 4.4.49)
__device__ __forceinline__ float atan2_fast(float y, float x) {
    float ax = fabsf(x), ay = fabsf(y);
    float mx = fmaxf(ax, ay), mn = fminf(ax, ay);
    float t  = mn * rcp_fast(mx);
    float s  = t * t;
    float p  = fmaf(s, fmaf(s, fmaf(s, fmaf(s, 0.0208351f, -0.0851330f),
                                       0.1801410f), -0.3302995f), 0.9998660f);
    float rr = p * t;
    rr = (ay > ax)   ? PIO2_F - rr : rr;
    rr = (x < 0.0f)  ? PI_F  - rr : rr;
    return __builtin_copysignf(rr, y);
}

// ---------------------------------------------------------------------------
// prep_kernel: one block, runs once per launch. Hoists ALL block-invariant
// work out of the 6250 main blocks (r5: -27%), now including the tanh table.
// ---------------------------------------------------------------------------
__global__ void prep_kernel(const float* __restrict__ logm,
                            const float* __restrict__ W1, const float* __restrict__ b1,
                            const float* __restrict__ W2, const float* __restrict__ b2,
                            const float* __restrict__ W3,
                            const int* __restrict__ senders, const int* __restrict__ receivers,
                            int* __restrict__ ws)
{
    const int t = threadIdx.x;                // 128 threads
    if (t < 64) {
        const int n  = t & 31, h = t >> 5;
        const int nu = 16 * (n >> 4) + 8 * ((n >> 2) & 1) + 4 * ((n >> 3) & 1) + (n & 3);
        const int c3 = n & 3;
        short8 a1, a2a, a2b, a3a, a3b;
        f32x16 cb2;
        #pragma unroll
        for (int j = 0; j < 8; ++j) {
            const int k = 8 * h + j;
            float w1v = 0.0f;
            if (h == 0) {
                if (j < 5)       w1v = W1[j * 32 + nu] * C2LOG2E;
                else if (j == 5) w1v = b1[nu] * C2LOG2E;
            }
            a1[j]  = bf16_rne(w1v);
            a2a[j] = bf16_rne(W2[k * 32 + nu] * C2LOG2E);
            a2b[j] = bf16_rne(W2[(16 + k) * 32 + nu] * C2LOG2E);
            a3a[j] = (c3 < 3) ? bf16_rne(W3[k * 3 + c3]) : (short)0;
            a3b[j] = (c3 < 3) ? bf16_rne(W3[(16 + k) * 3 + c3]) : (short)0;
        }
        #pragma unroll
        for (int r = 0; r < 16; ++r) {
            int neuron = (r < 8) ? (8 * h + r) : (16 + 8 * h + (r - 8));
            cb2[r] = b2[neuron] * C2LOG2E;
        }
        int4* wf = (int4*)ws;
        wf[0 * 64 + t] = *(int4*)&a1;
        wf[1 * 64 + t] = *(int4*)&a2a;
        wf[2 * 64 + t] = *(int4*)&a2b;
        wf[3 * 64 + t] = *(int4*)&a3a;
        wf[4 * 64 + t] = *(int4*)&a3b;
        int4* c4 = (int4*)&cb2;
        wf[5 * 64 + t] = c4[0];
        wf[6 * 64 + t] = c4[1];
        wf[7 * 64 + t] = c4[2];
        wf[8 * 64 + t] = c4[3];
    }
    if (t < NP) {
        float l = fminf(12.0f, fmaxf(-12.0f, logm[t]));
        ((float*)ws)[WS_EINV + t] = __expf(-l);
    }
    if (t < NE) {
        float lr = fminf(12.0f, fmaxf(-12.0f, logm[receivers[t]]));
        float ls = fminf(12.0f, fmaxf(-12.0f, logm[senders[t]]));
        ws[WS_MPAIR + t] = bf16pk2(lr, ls);
    }
    if (t < NP) {                             // signed edge table (9 per planet)
        int cnt = 0;
        for (int e = 0; e < NE; ++e) {
            if (receivers[e] == t) ws[WS_STAB + t * 9 + cnt++] =  (e + 1);
            if (senders[e]   == t) ws[WS_STAB + t * 9 + cnt++] = -(e + 1);
        }
        for (; cnt < 9; ++cnt) ws[WS_STAB + t * 9 + cnt] = 0;
    }
    // tanh table: entry i = bf16(tanh((i-2048) * ln2/256)), one-time.
    {
        unsigned short* tb = (unsigned short*)(ws + WS_TAB);
        for (int i = t; i < 4096; i += 128) {
            float xx = (float)(i - 2048) * 0.002707606174f;  // (ln2/2)/128
            tb[i] = (unsigned short)bf16_rne(tanhf(xx));
        }
    }
}

// r10 = r9 structure (session best) with table-tanh. VALU-issue was the
// bottleneck (80% busy, ~76% of it transcendental); the table moves tanh
// onto the LDS pipe.
__global__ __launch_bounds__(BLOCK, 4) void
learn_forces_kernel(const float* __restrict__ D_V,
                    const float* __restrict__ b3,
                    const int* __restrict__ ws,
                    float* __restrict__ out, int ntime)
{
    __shared__ float einv[NP];
    __shared__ int   stab[NP * 9];            // signed edge list per planet: +-(e+1)
    __shared__ int   mpair[NE];               // packed bf16 (lo=lm_recv, hi=lm_send)
    __shared__ float secart[3][EPB];          // SoA cartesian edge forces (8.64 KB)
    __shared__ unsigned short ttab[4096];     // bf16 tanh table (8 KB)

    const int tid  = threadIdx.x;
    const int wv   = tid >> 6, lane = tid & 63;
    const int h    = lane >> 5;

    // ---- block-invariant constants: 9 coalesced int4 loads from ws ------
    short8 a1, a2a, a2b, a3a, a3b;
    f32x16 cb2, zf16;
    {
        const int4* wf = (const int4*)ws;
        *(int4*)&a1  = wf[0 * 64 + lane];
        *(int4*)&a2a = wf[1 * 64 + lane];
        *(int4*)&a2b = wf[2 * 64 + lane];
        *(int4*)&a3a = wf[3 * 64 + lane];
        *(int4*)&a3b = wf[4 * 64 + lane];
        int4* c4 = (int4*)&cb2;
        c4[0] = wf[5 * 64 + lane];
        c4[1] = wf[6 * 64 + lane];
        c4[2] = wf[7 * 64 + lane];
        c4[3] = wf[8 * 64 + lane];
    }
    #pragma unroll
    for (int r = 0; r < 16; ++r) zf16[r] = 0.0f;

    // table copy: 512 int4 (8 KB), 2 per thread; L2-resident source
    {
        const int4* s4 = (const int4*)(ws + WS_TAB);
        int4* d4 = (int4*)ttab;
        #pragma unroll
        for (int i = 0; i < 2; ++i) d4[tid + i * BLOCK] = s4[tid + i * BLOCK];
    }

    if (tid < NP)     einv[tid]  = ((const float*)ws)[WS_EINV + tid];
    if (tid < NE)     mpair[tid] = ws[WS_MPAIR + tid];
    if (tid < NP * 9) stab[tid]  = ws[WS_STAB + tid];
    const float b30 = b3[0], b31 = b3[1], b32 = b3[2];

    const int idxg1 = ((lane & 31) | 32) * 4;  // group-1 source lane (32+n)
    __syncthreads();

    // software prefetch of first chunk's D_V; running pointer avoids 64-bit
    // index mul per chunk.
    const long ebase = (long)blockIdx.x * EPB;
    const int  e0i   = wv * 64 + lane;
    const float* dvp = D_V + (ebase + e0i) * 3;   // points at e_loc of chunk c
    int le = e0i % NE;                            // own local-edge id (mod 45)
    float xn = 1.f, yn = 0.f, zn = 0.f;
    if (e0i < EPB) { xn = dvp[0]; yn = dvp[1]; zn = dvp[2]; }

    for (int c = wv; c < NCHUNK; c += 4) {
        const int  e_loc  = c * 64 + lane;
        const bool active = e_loc < EPB;

        float x = xn, y = yn, z = zn;
        // prefetch next chunk (e_loc advances by 256; EPB<=NCHUNK*64 so the
        // single bound check suffices)
        dvp += 256 * 3;
        xn = 1.f; yn = 0.f; zn = 0.f;
        if (e_loc + 256 < EPB) { xn = dvp[0]; yn = dvp[1]; zn = dvp[2]; }

        // ---- own-edge features ------------------------------------------
        float ss  = fmaf(x, x, fmaf(y, y, z * z));
        float rsq = __builtin_amdgcn_rsqf(ss);
        float r   = ss * rsq;
        float zr  = fminf(1.0f, fmaxf(-1.0f, z * rsq));
        float th  = acos_fast(zr);
        float ph  = atan2_fast(y, x);

        int mp   = mpair[le];                              // lo=lmr, hi=lms
        le += 256 % NE;                                    // advance: (le+31)%45
        le  = (le >= NE) ? le - NE : le;
        int p_rt = bf16pk2(r, th);                         // k0,k1
        int p_pm = (int)__builtin_amdgcn_perm(             // lo=ph (k2), hi=lmr (k3)
                       (unsigned)mp, __float_as_uint(ph) + 0x8000u, 0x05040302u);
        int p_s1 = (int)(((unsigned)mp >> 16) | 0x3F800000u); // k4=lms, k5=1.0 (bias)

        // ---- group-1 transport: 3 bperms (group 0 is lane-local) --------
        int q_rt = bperm_i(idxg1, p_rt);
        int q_pm = bperm_i(idxg1, p_pm);
        int q_s1 = bperm_i(idxg1, p_s1);

        // B-frags: h=1 lanes carry garbage at k=8..15 — masked by A1==0 there
        short8 bf0, bf1;
        { int* b = (int*)&bf0; b[0] = p_rt; b[1] = p_pm; b[2] = p_s1; b[3] = 0; }
        { int* b = (int*)&bf1; b[0] = q_rt; b[1] = q_pm; b[2] = q_s1; b[3] = 0; }

        // ---- L1: one MFMA per 32-edge group -----------------------------
        f32x16 dA = MFMA32(a1, bf0, zf16);
        f32x16 dB = MFMA32(a1, bf1, zf16);

        // ---- L1 tanh (table) -> L2 (2 chained MFMAs per group) ----------
        short8 hA0, hA1, hB0, hB1;
        {
            int* p = (int*)&hA0; int* q2 = (int*)&hA1;
            p[0]  = tanh_pair_tab(ttab, dA[0],  dA[1]);  p[1]  = tanh_pair_tab(ttab, dA[2],  dA[3]);
            p[2]  = tanh_pair_tab(ttab, dA[4],  dA[5]);  p[3]  = tanh_pair_tab(ttab, dA[6],  dA[7]);
            q2[0] = tanh_pair_tab(ttab, dA[8],  dA[9]);  q2[1] = tanh_pair_tab(ttab, dA[10], dA[11]);
            q2[2] = tanh_pair_tab(ttab, dA[12], dA[13]); q2[3] = tanh_pair_tab(ttab, dA[14], dA[15]);
        }
        {
            int* p = (int*)&hB0; int* q2 = (int*)&hB1;
            p[0]  = tanh_pair_tab(ttab, dB[0],  dB[1]);  p[1]  = tanh_pair_tab(ttab, dB[2],  dB[3]);
            p[2]  = tanh_pair_tab(ttab, dB[4],  dB[5]);  p[3]  = tanh_pair_tab(ttab, dB[6],  dB[7]);
            q2[0] = tanh_pair_tab(ttab, dB[8],  dB[9]);  q2[1] = tanh_pair_tab(ttab, dB[10], dB[11]);
            q2[2] = tanh_pair_tab(ttab, dB[12], dB[13]); q2[3] = tanh_pair_tab(ttab, dB[14], dB[15]);
        }
        f32x16 eA = MFMA32(a2a, hA0, cb2);
        eA        = MFMA32(a2b, hA1, eA);
        f32x16 eB = MFMA32(a2a, hB0, cb2);
        eB        = MFMA32(a2b, hB1, eB);

        // ---- L2 tanh (table) -> L3 (2 chained MFMAs per group) ----------
        {
            int* p = (int*)&hA0; int* q2 = (int*)&hA1;
            p[0]  = tanh_pair_tab(ttab, eA[0],  eA[1]);  p[1]  = tanh_pair_tab(ttab, eA[2],  eA[3]);
            p[2]  = tanh_pair_tab(ttab, eA[4],  eA[5]);  p[3]  = tanh_pair_tab(ttab, eA[6],  eA[7]);
            q2[0] = tanh_pair_tab(ttab, eA[8],  eA[9]);  q2[1] = tanh_pair_tab(ttab, eA[10], eA[11]);
            q2[2] = tanh_pair_tab(ttab, eA[12], eA[13]); q2[3] = tanh_pair_tab(ttab, eA[14], eA[15]);
        }
        {
            int* p = (int*)&hB0; int* q2 = (int*)&hB1;
            p[0]  = tanh_pair_tab(ttab, eB[0],  eB[1]);  p[1]  = tanh_pair_tab(ttab, eB[2],  eB[3]);
            p[2]  = tanh_pair_tab(ttab, eB[4],  eB[5]);  p[3]  = tanh_pair_tab(ttab, eB[6],  eB[7]);
            q2[0] = tanh_pair_tab(ttab, eB[8],  eB[9]);  q2[1] = tanh_pair_tab(ttab, eB[10], eB[11]);
            q2[2] = tanh_pair_tab(ttab, eB[12], eB[13]); q2[3] = tanh_pair_tab(ttab, eB[14], eB[15]);
        }
        f32x16 oA = MFMA32(a3a, hA0, zf16);
        oA        = MFMA32(a3b, hA1, oA);
        f32x16 oB = MFMA32(a3a, hB0, zf16);
        oB        = MFMA32(a3b, hB1, oB);

        // ---- own edge = group h, column n: regs 0..2 = (e0,e1,e2) -------
        float e0 = (h ? oB[0] : oA[0]) + b30;
        float e1 = (h ? oB[1] : oA[1]) + b31;
        float e2 = (h ? oB[2] : oA[2]) + b32;

        // ---- sph -> cart, plain SoA LDS store ---------------------------
        float st = __sinf(e1), ct = __cosf(e1);
        float sp = __sinf(e2), cp = __cosf(e2);
        float am = e0 * st;
        f32x2 xy;
        {
            f32x2 cs; cs.x = cp; cs.y = sp;
            xy = cs * am;                      // v_pk_mul_f32
        }
        if (active) {
            secart[0][e_loc] = xy.x;
            secart[1][e_loc] = xy.y;
            secart[2][e_loc] = e0 * ct;
        }
    }
    __syncthreads();

    // ---- table-driven signed gather-sum: one (t, planet, comp) per thread
    const long t0g = (long)blockIdx.x * TS;
    for (int i = tid; i < TS * NP * 3; i += BLOCK) {
        int t  = i / (NP * 3);
        int pc = i - t * (NP * 3);
        int p  = pc / 3;
        int cc = pc - p * 3;
        const float* row = &secart[cc][t * NE];
        float s = 0.0f;
        #pragma unroll
        for (int j = 0; j < 9; ++j) {
            int es = stab[p * 9 + j];
            int e  = (es < 0 ? -es : es) - 1;
            float v = row[e];
            s += (es > 0) ? v : -v;
        }
        out[t0g * NP * 3 + i] = s * einv[p];   // contiguous 480-float range
    }
}

extern "C" void kernel_launch(void* const* d_in, const int* in_sizes, int n_in,
                              void* d_out, int out_size, void* d_ws, size_t ws_size,
                              hipStream_t stream) {
    const float* D_V  = (const float*)d_in[0];
    const float* logm = (const float*)d_in[1];
    const float* W1   = (const float*)d_in[2];
    const float* b1   = (const float*)d_in[3];
    const float* W2   = (const float*)d_in[4];
    const float* b2   = (const float*)d_in[5];
    const float* W3   = (const float*)d_in[6];
    const float* b3   = (const float*)d_in[7];
    const int* senders   = (const int*)d_in[8];
    const int* receivers = (const int*)d_in[9];

    int nedges = in_sizes[8];               // 45
    int ntime  = in_sizes[0] / 3 / nedges;  // 100000

    int* ws = (int*)d_ws;                   // needs ~18 KB

    prep_kernel<<<1, 128, 0, stream>>>(logm, W1, b1, W2, b2, W3,
                                       senders, receivers, ws);

    int nblocks = (ntime + TS - 1) / TS;    // 6250
    learn_forces_kernel<<<nblocks, BLOCK, 0, stream>>>(
        D_V, b3, ws, (float*)d_out, ntime);
}

// Round 11
// 180.158 us; speedup vs baseline: 1.0013x; 1.0013x over previous
//
#include <hip/hip_runtime.h>
#include <hip/hip_bf16.h>
#include <math.h>

#define NP 10
#define NE 45
#define TS 16                      // timesteps per block
#define EPB (TS * NE)              // 720 edges per block
#define BLOCK 256
#define NCHUNK ((EPB + 63) / 64)   // 12 chunks of 64 edge-slots

// workspace layout (ints): [0 .. 9*64*4) = 9 x 64 int4 weight frags,
// then einv (NP floats), mpair (NE ints), stab (NP*9 ints),
// then (16B-aligned) tanh table: 4096 ushorts (8 KB).
#define WS_EINV  (9 * 64 * 4)
#define WS_MPAIR (WS_EINV + NP)
#define WS_STAB  (WS_MPAIR + NE)
#define WS_TAB   2452              // >= WS_STAB+NP*9 (=2449), 16B-aligned

typedef __attribute__((ext_vector_type(8)))  short short8;   // 8 bf16 MFMA frag
typedef __attribute__((ext_vector_type(16))) float f32x16;   // 32x32 MFMA acc
typedef __attribute__((ext_vector_type(2)))  float f32x2;

#define C2LOG2E 2.885390081777927f   // 2*log2(e), folded into W1/W2 (+biases)
#define PI_F    3.14159265358979f
#define PIO2_F  1.57079632679490f

#define MFMA32(a, b, c) __builtin_amdgcn_mfma_f32_32x32x16_bf16(a, b, c, 0, 0, 0)

__device__ __forceinline__ float rcp_fast(float x) { return __builtin_amdgcn_rcpf(x); }

// Single-instruction bf16x2 pack (RNE). gfx950 has v_cvt_pk_bf16_f32 but no
// builtin (learn_hip m240). src0 -> low 16, src1 -> high 16.
__device__ __forceinline__ int cvt_pk_bf16(float lo, float hi) {
    int r;
    asm("v_cvt_pk_bf16_f32 %0, %1, %2" : "=v"(r) : "v"(lo), "v"(hi));
    return r;
}

// Table tanh (r10): moves tanh off the VALU pipe (r10 A/B: VALUBusy 80->67%)
// onto the LDS pipe. Index: i = clamp(s*128 + 2048.5, 0, 4095); entry
// i = bf16(tanh((i-2048)*ln2/256)); error <= 0.00135 < bf16 rounding (0.002).
__device__ __forceinline__ int tanh_pair_tab(const unsigned short* tt,
                                             float s0, float s1) {
    float i0 = fminf(4095.0f, fmaxf(0.0f, fmaf(s0, 128.0f, 2048.5f)));
    float i1 = fminf(4095.0f, fmaxf(0.0f, fmaf(s1, 128.0f, 2048.5f)));
    unsigned v0 = tt[(unsigned)i0];
    unsigned v1 = tt[(unsigned)i1];
    return (int)(v0 | (v1 << 16));
}

// 16 table-tanh -> two bf16x8 MFMA B-frags (regs 0..7 -> h0, 8..15 -> h1)
__device__ __forceinline__ void tanh16_tab(const unsigned short* tt,
                                           const f32x16& d, short8& h0, short8& h1) {
    int* p  = (int*)&h0;
    int* q2 = (int*)&h1;
    p[0]  = tanh_pair_tab(tt, d[0],  d[1]);  p[1]  = tanh_pair_tab(tt, d[2],  d[3]);
    p[2]  = tanh_pair_tab(tt, d[4],  d[5]);  p[3]  = tanh_pair_tab(tt, d[6],  d[7]);
    q2[0] = tanh_pair_tab(tt, d[8],  d[9]);  q2[1] = tanh_pair_tab(tt, d[10], d[11]);
    q2[2] = tanh_pair_tab(tt, d[12], d[13]); q2[3] = tanh_pair_tab(tt, d[14], d[15]);
}

__device__ __forceinline__ short bf16_rne(float f) {
    unsigned int u = __float_as_uint(f);
    return (short)((u + 0x7fffu + ((u >> 16) & 1u)) >> 16);
}
__device__ __forceinline__ int bf16pk2(float a, float b) {
    return cvt_pk_bf16(a, b);
}
__device__ __forceinline__ int bperm_i(int idx_bytes, int v) {
    return __builtin_amdgcn_ds_bpermute(idx_bytes, v);
}

// bf16-accuracy branch-free acos (A&S 4.4.45). Arg of sqrt is >=0 by
// construction; raw v_sqrt_f32 (avoids IEEE-correct fixup sequence).
__device__ __forceinline__ float acos_fast(float w) {
    float a = fabsf(w);
    float s = __builtin_amdgcn_sqrtf(1.0f - a);
    float p = fmaf(a, fmaf(a, fmaf(a, -0.0187293f, 0.0742610f), -0.2121144f), 1.5707288f);
    float v = s * p;
    return (w >= 0.0f) ? v : PI_F - v;
}
// bf16-accuracy branch-free atan2 (A&S 4.4.49)
__device__ __forceinline__ float atan2_fast(float y, float x) {
    float ax = fabsf(x), ay = fabsf(y);
    float mx = fmaxf(ax, ay), mn = fminf(ax, ay);
    float t  = mn * rcp_fast(mx);
    float s  = t * t;
    float p  = fmaf(s, fmaf(s, fmaf(s, fmaf(s, 0.0208351f, -0.0851330f),
                                       0.1801410f), -0.3302995f), 0.9998660f);
    float rr = p * t;
    rr = (ay > ax)   ? PIO2_F - rr : rr;
    rr = (x < 0.0f)  ? PI_F  - rr : rr;
    return __builtin_copysignf(rr, y);
}

// ---------------------------------------------------------------------------
// prep_kernel: one block, runs once per launch. Hoists ALL block-invariant
// work out of the 6250 main blocks (r5: -27%), incl. the tanh table.
// ---------------------------------------------------------------------------
__global__ void prep_kernel(const float* __restrict__ logm,
                            const float* __restrict__ W1, const float* __restrict__ b1,
                            const float* __restrict__ W2, const float* __restrict__ b2,
                            const float* __restrict__ W3,
                            const int* __restrict__ senders, const int* __restrict__ receivers,
                            int* __restrict__ ws)
{
    const int t = threadIdx.x;                // 128 threads
    if (t < 64) {
        const int n  = t & 31, h = t >> 5;
        const int nu = 16 * (n >> 4) + 8 * ((n >> 2) & 1) + 4 * ((n >> 3) & 1) + (n & 3);
        const int c3 = n & 3;
        short8 a1, a2a, a2b, a3a, a3b;
        f32x16 cb2;
        #pragma unroll
        for (int j = 0; j < 8; ++j) {
            const int k = 8 * h + j;
            float w1v = 0.0f;
            if (h == 0) {
                if (j < 5)       w1v = W1[j * 32 + nu] * C2LOG2E;
                else if (j == 5) w1v = b1[nu] * C2LOG2E;
            }
            a1[j]  = bf16_rne(w1v);
            a2a[j] = bf16_rne(W2[k * 32 + nu] * C2LOG2E);
            a2b[j] = bf16_rne(W2[(16 + k) * 32 + nu] * C2LOG2E);
            a3a[j] = (c3 < 3) ? bf16_rne(W3[k * 3 + c3]) : (short)0;
            a3b[j] = (c3 < 3) ? bf16_rne(W3[(16 + k) * 3 + c3]) : (short)0;
        }
        #pragma unroll
        for (int r = 0; r < 16; ++r) {
            int neuron = (r < 8) ? (8 * h + r) : (16 + 8 * h + (r - 8));
            cb2[r] = b2[neuron] * C2LOG2E;
        }
        int4* wf = (int4*)ws;
        wf[0 * 64 + t] = *(int4*)&a1;
        wf[1 * 64 + t] = *(int4*)&a2a;
        wf[2 * 64 + t] = *(int4*)&a2b;
        wf[3 * 64 + t] = *(int4*)&a3a;
        wf[4 * 64 + t] = *(int4*)&a3b;
        int4* c4 = (int4*)&cb2;
        wf[5 * 64 + t] = c4[0];
        wf[6 * 64 + t] = c4[1];
        wf[7 * 64 + t] = c4[2];
        wf[8 * 64 + t] = c4[3];
    }
    if (t < NP) {
        float l = fminf(12.0f, fmaxf(-12.0f, logm[t]));
        ((float*)ws)[WS_EINV + t] = __expf(-l);
    }
    if (t < NE) {
        float lr = fminf(12.0f, fmaxf(-12.0f, logm[receivers[t]]));
        float ls = fminf(12.0f, fmaxf(-12.0f, logm[senders[t]]));
        ws[WS_MPAIR + t] = bf16pk2(lr, ls);
    }
    if (t < NP) {                             // signed edge table (9 per planet)
        int cnt = 0;
        for (int e = 0; e < NE; ++e) {
            if (receivers[e] == t) ws[WS_STAB + t * 9 + cnt++] =  (e + 1);
            if (senders[e]   == t) ws[WS_STAB + t * 9 + cnt++] = -(e + 1);
        }
        for (; cnt < 9; ++cnt) ws[WS_STAB + t * 9 + cnt] = 0;
    }
    // tanh table: entry i = bf16(tanh((i-2048) * ln2/256)), one-time.
    {
        unsigned short* tb = (unsigned short*)(ws + WS_TAB);
        for (int i = t; i < 4096; i += 128) {
            float xx = (float)(i - 2048) * 0.002707606174f;  // (ln2/2)/128
            tb[i] = (unsigned short)bf16_rne(tanhf(xx));
        }
    }
}

// r11 = table tanh (r10) + sequential A-then-B MLP (r6 structure) to halve
// live acc chains (~112 -> ~48 AGPR) and raise waves/SIMD 3 -> 4-5.
// Regime change justifies re-testing r6's structure: r6 was flat because
// VALU issue was 80% saturated (no slots for extra waves); r10's table cut
// VALUBusy to 67% and turned the freed cycles into gather-latency STALL --
// extra waves now have slots to fill.
__global__ __launch_bounds__(BLOCK, 4) void
learn_forces_kernel(const float* __restrict__ D_V,
                    const float* __restrict__ b3,
                    const int* __restrict__ ws,
                    float* __restrict__ out, int ntime)
{
    __shared__ float einv[NP];
    __shared__ int   stab[NP * 9];            // signed edge list per planet: +-(e+1)
    __shared__ int   mpair[NE];               // packed bf16 (lo=lm_recv, hi=lm_send)
    __shared__ float secart[3][EPB];          // SoA cartesian edge forces (8.64 KB)
    __shared__ unsigned short ttab[4096];     // bf16 tanh table (8 KB)

    const int tid  = threadIdx.x;
    const int wv   = tid >> 6, lane = tid & 63;
    const int h    = lane >> 5;

    // ---- block-invariant constants: 9 coalesced int4 loads from ws ------
    short8 a1, a2a, a2b, a3a, a3b;
    f32x16 cb2, zf16;
    {
        const int4* wf = (const int4*)ws;
        *(int4*)&a1  = wf[0 * 64 + lane];
        *(int4*)&a2a = wf[1 * 64 + lane];
        *(int4*)&a2b = wf[2 * 64 + lane];
        *(int4*)&a3a = wf[3 * 64 + lane];
        *(int4*)&a3b = wf[4 * 64 + lane];
        int4* c4 = (int4*)&cb2;
        c4[0] = wf[5 * 64 + lane];
        c4[1] = wf[6 * 64 + lane];
        c4[2] = wf[7 * 64 + lane];
        c4[3] = wf[8 * 64 + lane];
    }
    #pragma unroll
    for (int r = 0; r < 16; ++r) zf16[r] = 0.0f;

    // table copy: 512 int4 (8 KB), 2 per thread; L2-resident source
    {
        const int4* s4 = (const int4*)(ws + WS_TAB);
        int4* d4 = (int4*)ttab;
        #pragma unroll
        for (int i = 0; i < 2; ++i) d4[tid + i * BLOCK] = s4[tid + i * BLOCK];
    }

    if (tid < NP)     einv[tid]  = ((const float*)ws)[WS_EINV + tid];
    if (tid < NE)     mpair[tid] = ws[WS_MPAIR + tid];
    if (tid < NP * 9) stab[tid]  = ws[WS_STAB + tid];
    const float b30 = b3[0], b31 = b3[1], b32 = b3[2];

    const int idxg1 = ((lane & 31) | 32) * 4;  // group-1 source lane (32+n)
    __syncthreads();

    // software prefetch of first chunk's D_V; running pointer avoids 64-bit
    // index mul per chunk.
    const long ebase = (long)blockIdx.x * EPB;
    const int  e0i   = wv * 64 + lane;
    const float* dvp = D_V + (ebase + e0i) * 3;   // points at e_loc of chunk c
    int le = e0i % NE;                            // own local-edge id (mod 45)
    float xn = 1.f, yn = 0.f, zn = 0.f;
    if (e0i < EPB) { xn = dvp[0]; yn = dvp[1]; zn = dvp[2]; }

    for (int c = wv; c < NCHUNK; c += 4) {
        const int  e_loc  = c * 64 + lane;
        const bool active = e_loc < EPB;

        float x = xn, y = yn, z = zn;
        // prefetch next chunk (e_loc advances by 256; EPB<=NCHUNK*64 so the
        // single bound check suffices)
        dvp += 256 * 3;
        xn = 1.f; yn = 0.f; zn = 0.f;
        if (e_loc + 256 < EPB) { xn = dvp[0]; yn = dvp[1]; zn = dvp[2]; }

        // ---- own-edge features ------------------------------------------
        float ss  = fmaf(x, x, fmaf(y, y, z * z));
        float rsq = __builtin_amdgcn_rsqf(ss);
        float r   = ss * rsq;
        float zr  = fminf(1.0f, fmaxf(-1.0f, z * rsq));
        float th  = acos_fast(zr);
        float ph  = atan2_fast(y, x);

        int mp   = mpair[le];                              // lo=lmr, hi=lms
        le += 256 % NE;                                    // advance: (le+31)%45
        le  = (le >= NE) ? le - NE : le;
        int p_rt = bf16pk2(r, th);                         // k0,k1
        int p_pm = (int)__builtin_amdgcn_perm(             // lo=ph (k2), hi=lmr (k3)
                       (unsigned)mp, __float_as_uint(ph) + 0x8000u, 0x05040302u);
        int p_s1 = (int)(((unsigned)mp >> 16) | 0x3F800000u); // k4=lms, k5=1.0 (bias)

        // ---- group-1 transport: 3 bperms (group 0 is lane-local) --------
        int q_rt = bperm_i(idxg1, p_rt);
        int q_pm = bperm_i(idxg1, p_pm);
        int q_s1 = bperm_i(idxg1, p_s1);

        // B-frags: h=1 lanes carry garbage at k=8..15 — masked by A1==0 there
        short8 bf0, bf1;
        { int* b = (int*)&bf0; b[0] = p_rt; b[1] = p_pm; b[2] = p_s1; b[3] = 0; }
        { int* b = (int*)&bf1; b[0] = q_rt; b[1] = q_pm; b[2] = q_s1; b[3] = 0; }

        // ---- group A: full MLP, ONE f32x16 acc live ---------------------
        float eA0, eA1, eA2;
        {
            short8 h0, h1;
            f32x16 acc = MFMA32(a1, bf0, zf16);
            tanh16_tab(ttab, acc, h0, h1);
            acc = MFMA32(a2a, h0, cb2);
            acc = MFMA32(a2b, h1, acc);
            tanh16_tab(ttab, acc, h0, h1);
            acc = MFMA32(a3a, h0, zf16);
            acc = MFMA32(a3b, h1, acc);
            eA0 = acc[0]; eA1 = acc[1]; eA2 = acc[2];
        }
        // keep scheduler from re-interleaving A and B (would re-inflate
        // the unified reg footprint back to 2+ live f32x16 chains)
        __builtin_amdgcn_sched_barrier(0);

        // ---- group B: full MLP, ONE f32x16 acc live ---------------------
        float eB0, eB1, eB2;
        {
            short8 h0, h1;
            f32x16 acc = MFMA32(a1, bf1, zf16);
            tanh16_tab(ttab, acc, h0, h1);
            acc = MFMA32(a2a, h0, cb2);
            acc = MFMA32(a2b, h1, acc);
            tanh16_tab(ttab, acc, h0, h1);
            acc = MFMA32(a3a, h0, zf16);
            acc = MFMA32(a3b, h1, acc);
            eB0 = acc[0]; eB1 = acc[1]; eB2 = acc[2];
        }

        // ---- own edge = group h, column n: regs 0..2 = (e0,e1,e2) -------
        float e0 = (h ? eB0 : eA0) + b30;
        float e1 = (h ? eB1 : eA1) + b31;
        float e2 = (h ? eB2 : eA2) + b32;

        // ---- sph -> cart, plain SoA LDS store ---------------------------
        float st = __sinf(e1), ct = __cosf(e1);
        float sp = __sinf(e2), cp = __cosf(e2);
        float am = e0 * st;
        f32x2 xy;
        {
            f32x2 cs; cs.x = cp; cs.y = sp;
            xy = cs * am;                      // v_pk_mul_f32
        }
        if (active) {
            secart[0][e_loc] = xy.x;
            secart[1][e_loc] = xy.y;
            secart[2][e_loc] = e0 * ct;
        }
    }
    __syncthreads();

    // ---- table-driven signed gather-sum: one (t, planet, comp) per thread
    const long t0g = (long)blockIdx.x * TS;
    for (int i = tid; i < TS * NP * 3; i += BLOCK) {
        int t  = i / (NP * 3);
        int pc = i - t * (NP * 3);
        int p  = pc / 3;
        int cc = pc - p * 3;
        const float* row = &secart[cc][t * NE];
        float s = 0.0f;
        #pragma unroll
        for (int j = 0; j < 9; ++j) {
            int es = stab[p * 9 + j];
            int e  = (es < 0 ? -es : es) - 1;
            float v = row[e];
            s += (es > 0) ? v : -v;
        }
        out[t0g * NP * 3 + i] = s * einv[p];   // contiguous 480-float range
    }
}

extern "C" void kernel_launch(void* const* d_in, const int* in_sizes, int n_in,
                              void* d_out, int out_size, void* d_ws, size_t ws_size,
                              hipStream_t stream) {
    const float* D_V  = (const float*)d_in[0];
    const float* logm = (const float*)d_in[1];
    const float* W1   = (const float*)d_in[2];
    const float* b1   = (const float*)d_in[3];
    const float* W2   = (const float*)d_in[4];
    const float* b2   = (const float*)d_in[5];
    const float* W3   = (const float*)d_in[6];
    const float* b3   = (const float*)d_in[7];
    const int* senders   = (const int*)d_in[8];
    const int* receivers = (const int*)d_in[9];

    int nedges = in_sizes[8];               // 45
    int ntime  = in_sizes[0] / 3 / nedges;  // 100000

    int* ws = (int*)d_ws;                   // needs ~18 KB

    prep_kernel<<<1, 128, 0, stream>>>(logm, W1, b1, W2, b2, W3,
                                       senders, receivers, ws);

    int nblocks = (ntime + TS - 1) / TS;    // 6250
    learn_forces_kernel<<<nblocks, BLOCK, 0, stream>>>(
        D_V, b3, ws, (float*)d_out, ntime);
}

// Round 12
// 178.046 us; speedup vs baseline: 1.0131x; 1.0119x over previous
//
#include <hip/hip_runtime.h>
#include <hip/hip_bf16.h>
#include <math.h>

#define NP 10
#define NE 45
#define TS 16                      // timesteps per block
#define EPB (TS * NE)              // 720 edges per block
#define BLOCK 256
#define NCHUNK ((EPB + 63) / 64)   // 12 chunks of 64 edge-slots

// workspace layout (ints): [0 .. 9*64*4) = 9 x 64 int4 weight frags,
// then einv (NP floats), mpair (NE ints), stab (NP*9 ints),
// then (16B-aligned) tanh table: 4096 ushorts (8 KB).
#define WS_EINV  (9 * 64 * 4)
#define WS_MPAIR (WS_EINV + NP)
#define WS_STAB  (WS_MPAIR + NE)
#define WS_TAB   2452              // >= WS_STAB+NP*9 (=2449), 16B-aligned

typedef __attribute__((ext_vector_type(8)))  short short8;   // 8 bf16 MFMA frag
typedef __attribute__((ext_vector_type(16))) float f32x16;   // 32x32 MFMA acc
typedef __attribute__((ext_vector_type(2)))  float f32x2;

#define C2LOG2E 2.885390081777927f   // 2*log2(e), folded into W1/W2 (+biases)
#define PI_F    3.14159265358979f
#define PIO2_F  1.57079632679490f

#define MFMA32(a, b, c) __builtin_amdgcn_mfma_f32_32x32x16_bf16(a, b, c, 0, 0, 0)

__device__ __forceinline__ float rcp_fast(float x) { return __builtin_amdgcn_rcpf(x); }

// Single-instruction bf16x2 pack (RNE). gfx950 has v_cvt_pk_bf16_f32 but no
// builtin (learn_hip m240). src0 -> low 16, src1 -> high 16.
__device__ __forceinline__ int cvt_pk_bf16(float lo, float hi) {
    int r;
    asm("v_cvt_pk_bf16_f32 %0, %1, %2" : "=v"(r) : "v"(lo), "v"(hi));
    return r;
}

// Table tanh (r10): moves tanh off the VALU pipe (r10 A/B: VALUBusy 80->67%)
// onto the LDS pipe. Index: i = clamp(s*128 + 2048.5, 0, 4095); entry
// i = bf16(tanh((i-2048)*ln2/256)); error <= 0.00135 < bf16 rounding (0.002).
__device__ __forceinline__ int tanh_pair_tab(const unsigned short* tt,
                                             float s0, float s1) {
    float i0 = fminf(4095.0f, fmaxf(0.0f, fmaf(s0, 128.0f, 2048.5f)));
    float i1 = fminf(4095.0f, fmaxf(0.0f, fmaf(s1, 128.0f, 2048.5f)));
    unsigned v0 = tt[(unsigned)i0];
    unsigned v1 = tt[(unsigned)i1];
    return (int)(v0 | (v1 << 16));
}

// 16 table-tanh -> two bf16x8 MFMA B-frags (regs 0..7 -> h0, 8..15 -> h1)
__device__ __forceinline__ void tanh16_tab(const unsigned short* tt,
                                           const f32x16& d, short8& h0, short8& h1) {
    int* p  = (int*)&h0;
    int* q2 = (int*)&h1;
    p[0]  = tanh_pair_tab(tt, d[0],  d[1]);  p[1]  = tanh_pair_tab(tt, d[2],  d[3]);
    p[2]  = tanh_pair_tab(tt, d[4],  d[5]);  p[3]  = tanh_pair_tab(tt, d[6],  d[7]);
    q2[0] = tanh_pair_tab(tt, d[8],  d[9]);  q2[1] = tanh_pair_tab(tt, d[10], d[11]);
    q2[2] = tanh_pair_tab(tt, d[12], d[13]); q2[3] = tanh_pair_tab(tt, d[14], d[15]);
}

__device__ __forceinline__ short bf16_rne(float f) {
    unsigned int u = __float_as_uint(f);
    return (short)((u + 0x7fffu + ((u >> 16) & 1u)) >> 16);
}
__device__ __forceinline__ int bf16pk2(float a, float b) {
    return cvt_pk_bf16(a, b);
}
__device__ __forceinline__ int bperm_i(int idx_bytes, int v) {
    return __builtin_amdgcn_ds_bpermute(idx_bytes, v);
}

// bf16-accuracy branch-free acos (A&S 4.4.45). Arg of sqrt is >=0 by
// construction; raw v_sqrt_f32 (avoids IEEE-correct fixup sequence).
__device__ __forceinline__ float acos_fast(float w) {
    float a = fabsf(w);
    float s = __builtin_amdgcn_sqrtf(1.0f - a);
    float p = fmaf(a, fmaf(a, fmaf(a, -0.0187293f, 0.0742610f), -0.2121144f), 1.5707288f);
    float v = s * p;
    return (w >= 0.0f) ? v : PI_F - v;
}
// bf16-accuracy branch-free atan2 (A&S 4.4.49)
__device__ __forceinline__ float atan2_fast(float y, float x) {
    float ax = fabsf(x), ay = fabsf(y);
    float mx = fmaxf(ax, ay), mn = fminf(ax, ay);
    float t  = mn * rcp_fast(mx);
    float s  = t * t;
    float p  = fmaf(s, fmaf(s, fmaf(s, fmaf(s, 0.0208351f, -0.0851330f),
                                       0.1801410f), -0.3302995f), 0.9998660f);
    float rr = p * t;
    rr = (ay > ax)   ? PIO2_F - rr : rr;
    rr = (x < 0.0f)  ? PI_F  - rr : rr;
    return __builtin_copysignf(rr, y);
}

// ---------------------------------------------------------------------------
// prep_kernel: one block, runs once per launch. Hoists ALL block-invariant
// work out of the 6250 main blocks (r5: -27%), incl. the tanh table.
// ---------------------------------------------------------------------------
__global__ void prep_kernel(const float* __restrict__ logm,
                            const float* __restrict__ W1, const float* __restrict__ b1,
                            const float* __restrict__ W2, const float* __restrict__ b2,
                            const float* __restrict__ W3,
                            const int* __restrict__ senders, const int* __restrict__ receivers,
                            int* __restrict__ ws)
{
    const int t = threadIdx.x;                // 128 threads
    if (t < 64) {
        const int n  = t & 31, h = t >> 5;
        const int nu = 16 * (n >> 4) + 8 * ((n >> 2) & 1) + 4 * ((n >> 3) & 1) + (n & 3);
        const int c3 = n & 3;
        short8 a1, a2a, a2b, a3a, a3b;
        f32x16 cb2;
        #pragma unroll
        for (int j = 0; j < 8; ++j) {
            const int k = 8 * h + j;
            float w1v = 0.0f;
            if (h == 0) {
                if (j < 5)       w1v = W1[j * 32 + nu] * C2LOG2E;
                else if (j == 5) w1v = b1[nu] * C2LOG2E;
            }
            a1[j]  = bf16_rne(w1v);
            a2a[j] = bf16_rne(W2[k * 32 + nu] * C2LOG2E);
            a2b[j] = bf16_rne(W2[(16 + k) * 32 + nu] * C2LOG2E);
            a3a[j] = (c3 < 3) ? bf16_rne(W3[k * 3 + c3]) : (short)0;
            a3b[j] = (c3 < 3) ? bf16_rne(W3[(16 + k) * 3 + c3]) : (short)0;
        }
        #pragma unroll
        for (int r = 0; r < 16; ++r) {
            int neuron = (r < 8) ? (8 * h + r) : (16 + 8 * h + (r - 8));
            cb2[r] = b2[neuron] * C2LOG2E;
        }
        int4* wf = (int4*)ws;
        wf[0 * 64 + t] = *(int4*)&a1;
        wf[1 * 64 + t] = *(int4*)&a2a;
        wf[2 * 64 + t] = *(int4*)&a2b;
        wf[3 * 64 + t] = *(int4*)&a3a;
        wf[4 * 64 + t] = *(int4*)&a3b;
        int4* c4 = (int4*)&cb2;
        wf[5 * 64 + t] = c4[0];
        wf[6 * 64 + t] = c4[1];
        wf[7 * 64 + t] = c4[2];
        wf[8 * 64 + t] = c4[3];
    }
    if (t < NP) {
        float l = fminf(12.0f, fmaxf(-12.0f, logm[t]));
        ((float*)ws)[WS_EINV + t] = __expf(-l);
    }
    if (t < NE) {
        float lr = fminf(12.0f, fmaxf(-12.0f, logm[receivers[t]]));
        float ls = fminf(12.0f, fmaxf(-12.0f, logm[senders[t]]));
        ws[WS_MPAIR + t] = bf16pk2(lr, ls);
    }
    if (t < NP) {                             // signed edge table (9 per planet)
        int cnt = 0;
        for (int e = 0; e < NE; ++e) {
            if (receivers[e] == t) ws[WS_STAB + t * 9 + cnt++] =  (e + 1);
            if (senders[e]   == t) ws[WS_STAB + t * 9 + cnt++] = -(e + 1);
        }
        for (; cnt < 9; ++cnt) ws[WS_STAB + t * 9 + cnt] = 0;
    }
    // tanh table: entry i = bf16(tanh((i-2048) * ln2/256)), one-time.
    {
        unsigned short* tb = (unsigned short*)(ws + WS_TAB);
        for (int i = t; i < 4096; i += 128) {
            float xx = (float)(i - 2048) * 0.002707606174f;  // (ln2/2)/128
            tb[i] = (unsigned short)bf16_rne(tanhf(xx));
        }
    }
}

// r12 = r11 with __launch_bounds__(BLOCK, 5). r11 budget: wall ~2300cy/chunk
// vs pipe floor ~1800 (LDS) / ~1580 (VALU) -> ~500cy stall gap. Occupancy
// stuck at 3.8 waves/SIMD because (.,4) let the allocator use ~108 unified
// regs; actual need ~92 fits the 5-wave budget (102). Force it.
__global__ __launch_bounds__(BLOCK, 5) void
learn_forces_kernel(const float* __restrict__ D_V,
                    const float* __restrict__ b3,
                    const int* __restrict__ ws,
                    float* __restrict__ out, int ntime)
{
    __shared__ float einv[NP];
    __shared__ int   stab[NP * 9];            // signed edge list per planet: +-(e+1)
    __shared__ int   mpair[NE];               // packed bf16 (lo=lm_recv, hi=lm_send)
    __shared__ float secart[3][EPB];          // SoA cartesian edge forces (8.64 KB)
    __shared__ unsigned short ttab[4096];     // bf16 tanh table (8 KB)

    const int tid  = threadIdx.x;
    const int wv   = tid >> 6, lane = tid & 63;
    const int h    = lane >> 5;

    // ---- block-invariant constants: 9 coalesced int4 loads from ws ------
    short8 a1, a2a, a2b, a3a, a3b;
    f32x16 cb2, zf16;
    {
        const int4* wf = (const int4*)ws;
        *(int4*)&a1  = wf[0 * 64 + lane];
        *(int4*)&a2a = wf[1 * 64 + lane];
        *(int4*)&a2b = wf[2 * 64 + lane];
        *(int4*)&a3a = wf[3 * 64 + lane];
        *(int4*)&a3b = wf[4 * 64 + lane];
        int4* c4 = (int4*)&cb2;
        c4[0] = wf[5 * 64 + lane];
        c4[1] = wf[6 * 64 + lane];
        c4[2] = wf[7 * 64 + lane];
        c4[3] = wf[8 * 64 + lane];
    }
    #pragma unroll
    for (int r = 0; r < 16; ++r) zf16[r] = 0.0f;

    // table copy: 512 int4 (8 KB), 2 per thread; L2-resident source
    {
        const int4* s4 = (const int4*)(ws + WS_TAB);
        int4* d4 = (int4*)ttab;
        #pragma unroll
        for (int i = 0; i < 2; ++i) d4[tid + i * BLOCK] = s4[tid + i * BLOCK];
    }

    if (tid < NP)     einv[tid]  = ((const float*)ws)[WS_EINV + tid];
    if (tid < NE)     mpair[tid] = ws[WS_MPAIR + tid];
    if (tid < NP * 9) stab[tid]  = ws[WS_STAB + tid];
    const float b30 = b3[0], b31 = b3[1], b32 = b3[2];

    const int idxg1 = ((lane & 31) | 32) * 4;  // group-1 source lane (32+n)
    __syncthreads();

    // software prefetch of first chunk's D_V; running pointer avoids 64-bit
    // index mul per chunk.
    const long ebase = (long)blockIdx.x * EPB;
    const int  e0i   = wv * 64 + lane;
    const float* dvp = D_V + (ebase + e0i) * 3;   // points at e_loc of chunk c
    int le = e0i % NE;                            // own local-edge id (mod 45)
    float xn = 1.f, yn = 0.f, zn = 0.f;
    if (e0i < EPB) { xn = dvp[0]; yn = dvp[1]; zn = dvp[2]; }

    for (int c = wv; c < NCHUNK; c += 4) {
        const int  e_loc  = c * 64 + lane;
        const bool active = e_loc < EPB;

        float x = xn, y = yn, z = zn;
        // prefetch next chunk (e_loc advances by 256; EPB<=NCHUNK*64 so the
        // single bound check suffices)
        dvp += 256 * 3;
        xn = 1.f; yn = 0.f; zn = 0.f;
        if (e_loc + 256 < EPB) { xn = dvp[0]; yn = dvp[1]; zn = dvp[2]; }

        // ---- own-edge features ------------------------------------------
        float ss  = fmaf(x, x, fmaf(y, y, z * z));
        float rsq = __builtin_amdgcn_rsqf(ss);
        float r   = ss * rsq;
        float zr  = fminf(1.0f, fmaxf(-1.0f, z * rsq));
        float th  = acos_fast(zr);
        float ph  = atan2_fast(y, x);

        int mp   = mpair[le];                              // lo=lmr, hi=lms
        le += 256 % NE;                                    // advance: (le+31)%45
        le  = (le >= NE) ? le - NE : le;
        int p_rt = bf16pk2(r, th);                         // k0,k1
        int p_pm = (int)__builtin_amdgcn_perm(             // lo=ph (k2), hi=lmr (k3)
                       (unsigned)mp, __float_as_uint(ph) + 0x8000u, 0x05040302u);
        int p_s1 = (int)(((unsigned)mp >> 16) | 0x3F800000u); // k4=lms, k5=1.0 (bias)

        // ---- group-1 transport: 3 bperms (group 0 is lane-local) --------
        int q_rt = bperm_i(idxg1, p_rt);
        int q_pm = bperm_i(idxg1, p_pm);
        int q_s1 = bperm_i(idxg1, p_s1);

        // B-frags: h=1 lanes carry garbage at k=8..15 — masked by A1==0 there
        short8 bf0, bf1;
        { int* b = (int*)&bf0; b[0] = p_rt; b[1] = p_pm; b[2] = p_s1; b[3] = 0; }
        { int* b = (int*)&bf1; b[0] = q_rt; b[1] = q_pm; b[2] = q_s1; b[3] = 0; }

        // ---- group A: full MLP, ONE f32x16 acc live ---------------------
        float eA0, eA1, eA2;
        {
            short8 h0, h1;
            f32x16 acc = MFMA32(a1, bf0, zf16);
            tanh16_tab(ttab, acc, h0, h1);
            acc = MFMA32(a2a, h0, cb2);
            acc = MFMA32(a2b, h1, acc);
            tanh16_tab(ttab, acc, h0, h1);
            acc = MFMA32(a3a, h0, zf16);
            acc = MFMA32(a3b, h1, acc);
            eA0 = acc[0]; eA1 = acc[1]; eA2 = acc[2];
        }
        // keep scheduler from re-interleaving A and B (would re-inflate
        // the unified reg footprint back to 2+ live f32x16 chains)
        __builtin_amdgcn_sched_barrier(0);

        // ---- group B: full MLP, ONE f32x16 acc live ---------------------
        float eB0, eB1, eB2;
        {
            short8 h0, h1;
            f32x16 acc = MFMA32(a1, bf1, zf16);
            tanh16_tab(ttab, acc, h0, h1);
            acc = MFMA32(a2a, h0, cb2);
            acc = MFMA32(a2b, h1, acc);
            tanh16_tab(ttab, acc, h0, h1);
            acc = MFMA32(a3a, h0, zf16);
            acc = MFMA32(a3b, h1, acc);
            eB0 = acc[0]; eB1 = acc[1]; eB2 = acc[2];
        }

        // ---- own edge = group h, column n: regs 0..2 = (e0,e1,e2) -------
        float e0 = (h ? eB0 : eA0) + b30;
        float e1 = (h ? eB1 : eA1) + b31;
        float e2 = (h ? eB2 : eA2) + b32;

        // ---- sph -> cart, plain SoA LDS store ---------------------------
        float st = __sinf(e1), ct = __cosf(e1);
        float sp = __sinf(e2), cp = __cosf(e2);
        float am = e0 * st;
        f32x2 xy;
        {
            f32x2 cs; cs.x = cp; cs.y = sp;
            xy = cs * am;                      // v_pk_mul_f32
        }
        if (active) {
            secart[0][e_loc] = xy.x;
            secart[1][e_loc] = xy.y;
            secart[2][e_loc] = e0 * ct;
        }
    }
    __syncthreads();

    // ---- table-driven signed gather-sum: one (t, planet, comp) per thread
    const long t0g = (long)blockIdx.x * TS;
    for (int i = tid; i < TS * NP * 3; i += BLOCK) {
        int t  = i / (NP * 3);
        int pc = i - t * (NP * 3);
        int p  = pc / 3;
        int cc = pc - p * 3;
        const float* row = &secart[cc][t * NE];
        float s = 0.0f;
        #pragma unroll
        for (int j = 0; j < 9; ++j) {
            int es = stab[p * 9 + j];
            int e  = (es < 0 ? -es : es) - 1;
            float v = row[e];
            s += (es > 0) ? v : -v;
        }
        out[t0g * NP * 3 + i] = s * einv[p];   // contiguous 480-float range
    }
}

extern "C" void kernel_launch(void* const* d_in, const int* in_sizes, int n_in,
                              void* d_out, int out_size, void* d_ws, size_t ws_size,
                              hipStream_t stream) {
    const float* D_V  = (const float*)d_in[0];
    const float* logm = (const float*)d_in[1];
    const float* W1   = (const float*)d_in[2];
    const float* b1   = (const float*)d_in[3];
    const float* W2   = (const float*)d_in[4];
    const float* b2   = (const float*)d_in[5];
    const float* W3   = (const float*)d_in[6];
    const float* b3   = (const float*)d_in[7];
    const int* senders   = (const int*)d_in[8];
    const int* receivers = (const int*)d_in[9];

    int nedges = in_sizes[8];               // 45
    int ntime  = in_sizes[0] / 3 / nedges;  // 100000

    int* ws = (int*)d_ws;                   // needs ~18 KB

    prep_kernel<<<1, 128, 0, stream>>>(logm, W1, b1, W2, b2, W3,
                                       senders, receivers, ws);

    int nblocks = (ntime + TS - 1) / TS;    // 6250
    learn_forces_kernel<<<nblocks, BLOCK, 0, stream>>>(
        D_V, b3, ws, (float*)d_out, ntime);
}

// Round 13
// 170.421 us; speedup vs baseline: 1.0585x; 1.0447x over previous
//
#include <hip/hip_runtime.h>
#include <hip/hip_bf16.h>
#include <math.h>

#define NP 10
#define NE 45
#define TS 16                      // timesteps per block
#define EPB (TS * NE)              // 720 edges per block
#define BLOCK 256
#define NCHUNK ((EPB + 63) / 64)   // 12 chunks of 64 edge-slots

// workspace layout (ints): [0 .. 9*64*4) = 9 x 64 int4 weight frags,
// then einv (NP floats), mpair (NE ints), stab (NP*9 ints),
// then (16B-aligned) tanh table: 4096 ushorts (8 KB).
#define WS_EINV  (9 * 64 * 4)
#define WS_MPAIR (WS_EINV + NP)
#define WS_STAB  (WS_MPAIR + NE)
#define WS_TAB   2452              // >= WS_STAB+NP*9 (=2449), 16B-aligned

typedef __attribute__((ext_vector_type(8)))  short short8;   // 8 bf16 MFMA frag
typedef __attribute__((ext_vector_type(16))) float f32x16;   // 32x32 MFMA acc
typedef __attribute__((ext_vector_type(2)))  float f32x2;

#define C2LOG2E 2.885390081777927f   // 2*log2(e), folded into W1/W2 (+biases)
#define PI_F    3.14159265358979f
#define PIO2_F  1.57079632679490f

#define MFMA32(a, b, c) __builtin_amdgcn_mfma_f32_32x32x16_bf16(a, b, c, 0, 0, 0)

__device__ __forceinline__ float rcp_fast(float x) { return __builtin_amdgcn_rcpf(x); }

// Single-instruction bf16x2 pack (RNE). gfx950 has v_cvt_pk_bf16_f32 but no
// builtin (learn_hip m240). src0 -> low 16, src1 -> high 16.
__device__ __forceinline__ int cvt_pk_bf16(float lo, float hi) {
    int r;
    asm("v_cvt_pk_bf16_f32 %0, %1, %2" : "=v"(r) : "v"(lo), "v"(hi));
    return r;
}

// Table tanh: LDS-pipe path. Index: i = clamp(s*128 + 2048.5, 0, 4095);
// entry i = bf16(tanh((i-2048)*ln2/256)); err <= 0.00135 < bf16 rounding.
__device__ __forceinline__ int tanh_pair_tab(const unsigned short* tt,
                                             float s0, float s1) {
    float i0 = fminf(4095.0f, fmaxf(0.0f, fmaf(s0, 128.0f, 2048.5f)));
    float i1 = fminf(4095.0f, fmaxf(0.0f, fmaf(s1, 128.0f, 2048.5f)));
    unsigned v0 = tt[(unsigned)i0];
    unsigned v1 = tt[(unsigned)i1];
    return (int)(v0 | (v1 << 16));
}

// Exp tanh: VALU/trans-pipe path. tanh(x) = 1 - 2/(e^{2x}+1), e^{2x}=exp2(s)
// with s pre-scaled by 2log2e (folded into weights). ~3 trans (@5.6cy,
// r9<->r10 calibrated) + ~7 full-rate.
__device__ __forceinline__ int tanh_pair_exp(float s0, float s1) {
    f32x2 e;
    e.x = __builtin_amdgcn_exp2f(s0);
    e.y = __builtin_amdgcn_exp2f(s1);
    f32x2 f = e + 1.0f;
    float r   = rcp_fast(f.x * f.y);
    float m2r = -2.0f * r;
    float t0  = fmaf(f.y, m2r, 1.0f);         // 1 - 2/f.x
    float t1  = fmaf(f.x, m2r, 1.0f);         // 1 - 2/f.y
    return cvt_pk_bf16(t0, t1);
}

// HYBRID tanh16 (r13): the per-CU LDS pipe (shared by 4 SIMDs) is the wall —
// r10-12's all-table put 64 gathers/chunk x 4 waves x ~10.6cy = 2714 cy/CU
// per chunk-period = the measured 2692cy wall, while VALU sat at 69%.
// Split 5 table + 3 exp per 8 pairs (balance point of the two pipes per the
// calibrated costs: exp ~30.8cy VALU; table ~18cy VALU + 21cy LDS).
// Table pairs issue FIRST so gather latency hides under exp VALU work.
__device__ __forceinline__ void tanh16_hyb(const unsigned short* tt,
                                           const f32x16& d, short8& h0, short8& h1) {
    int* p  = (int*)&h0;
    int* q2 = (int*)&h1;
    // 5 table pairs (LDS): issue early
    p[0]  = tanh_pair_tab(tt, d[0],  d[1]);
    p[1]  = tanh_pair_tab(tt, d[2],  d[3]);
    p[2]  = tanh_pair_tab(tt, d[4],  d[5]);
    p[3]  = tanh_pair_tab(tt, d[6],  d[7]);
    q2[0] = tanh_pair_tab(tt, d[8],  d[9]);
    // 3 exp pairs (VALU/trans): overlap with gathers in flight
    q2[1] = tanh_pair_exp(d[10], d[11]);
    q2[2] = tanh_pair_exp(d[12], d[13]);
    q2[3] = tanh_pair_exp(d[14], d[15]);
}

__device__ __forceinline__ short bf16_rne(float f) {
    unsigned int u = __float_as_uint(f);
    return (short)((u + 0x7fffu + ((u >> 16) & 1u)) >> 16);
}
__device__ __forceinline__ int bf16pk2(float a, float b) {
    return cvt_pk_bf16(a, b);
}
__device__ __forceinline__ int bperm_i(int idx_bytes, int v) {
    return __builtin_amdgcn_ds_bpermute(idx_bytes, v);
}

// bf16-accuracy branch-free acos (A&S 4.4.45). Arg of sqrt is >=0 by
// construction; raw v_sqrt_f32 (avoids IEEE-correct fixup sequence).
__device__ __forceinline__ float acos_fast(float w) {
    float a = fabsf(w);
    float s = __builtin_amdgcn_sqrtf(1.0f - a);
    float p = fmaf(a, fmaf(a, fmaf(a, -0.0187293f, 0.0742610f), -0.2121144f), 1.5707288f);
    float v = s * p;
    return (w >= 0.0f) ? v : PI_F - v;
}
// bf16-accuracy branch-free atan2 (A&S 4.4.49)
__device__ __forceinline__ float atan2_fast(float y, float x) {
    float ax = fabsf(x), ay = fabsf(y);
    float mx = fmaxf(ax, ay), mn = fminf(ax, ay);
    float t  = mn * rcp_fast(mx);
    float s  = t * t;
    float p  = fmaf(s, fmaf(s, fmaf(s, fmaf(s, 0.0208351f, -0.0851330f),
                                       0.1801410f), -0.3302995f), 0.9998660f);
    float rr = p * t;
    rr = (ay > ax)   ? PIO2_F - rr : rr;
    rr = (x < 0.0f)  ? PI_F  - rr : rr;
    return __builtin_copysignf(rr, y);
}

// ---------------------------------------------------------------------------
// prep_kernel: one block, runs once per launch. Hoists ALL block-invariant
// work out of the 6250 main blocks (r5: -27%), incl. the tanh table.
// ---------------------------------------------------------------------------
__global__ void prep_kernel(const float* __restrict__ logm,
                            const float* __restrict__ W1, const float* __restrict__ b1,
                            const float* __restrict__ W2, const float* __restrict__ b2,
                            const float* __restrict__ W3,
                            const int* __restrict__ senders, const int* __restrict__ receivers,
                            int* __restrict__ ws)
{
    const int t = threadIdx.x;                // 128 threads
    if (t < 64) {
        const int n  = t & 31, h = t >> 5;
        const int nu = 16 * (n >> 4) + 8 * ((n >> 2) & 1) + 4 * ((n >> 3) & 1) + (n & 3);
        const int c3 = n & 3;
        short8 a1, a2a, a2b, a3a, a3b;
        f32x16 cb2;
        #pragma unroll
        for (int j = 0; j < 8; ++j) {
            const int k = 8 * h + j;
            float w1v = 0.0f;
            if (h == 0) {
                if (j < 5)       w1v = W1[j * 32 + nu] * C2LOG2E;
                else if (j == 5) w1v = b1[nu] * C2LOG2E;
            }
            a1[j]  = bf16_rne(w1v);
            a2a[j] = bf16_rne(W2[k * 32 + nu] * C2LOG2E);
            a2b[j] = bf16_rne(W2[(16 + k) * 32 + nu] * C2LOG2E);
            a3a[j] = (c3 < 3) ? bf16_rne(W3[k * 3 + c3]) : (short)0;
            a3b[j] = (c3 < 3) ? bf16_rne(W3[(16 + k) * 3 + c3]) : (short)0;
        }
        #pragma unroll
        for (int r = 0; r < 16; ++r) {
            int neuron = (r < 8) ? (8 * h + r) : (16 + 8 * h + (r - 8));
            cb2[r] = b2[neuron] * C2LOG2E;
        }
        int4* wf = (int4*)ws;
        wf[0 * 64 + t] = *(int4*)&a1;
        wf[1 * 64 + t] = *(int4*)&a2a;
        wf[2 * 64 + t] = *(int4*)&a2b;
        wf[3 * 64 + t] = *(int4*)&a3a;
        wf[4 * 64 + t] = *(int4*)&a3b;
        int4* c4 = (int4*)&cb2;
        wf[5 * 64 + t] = c4[0];
        wf[6 * 64 + t] = c4[1];
        wf[7 * 64 + t] = c4[2];
        wf[8 * 64 + t] = c4[3];
    }
    if (t < NP) {
        float l = fminf(12.0f, fmaxf(-12.0f, logm[t]));
        ((float*)ws)[WS_EINV + t] = __expf(-l);
    }
    if (t < NE) {
        float lr = fminf(12.0f, fmaxf(-12.0f, logm[receivers[t]]));
        float ls = fminf(12.0f, fmaxf(-12.0f, logm[senders[t]]));
        ws[WS_MPAIR + t] = bf16pk2(lr, ls);
    }
    if (t < NP) {                             // signed edge table (9 per planet)
        int cnt = 0;
        for (int e = 0; e < NE; ++e) {
            if (receivers[e] == t) ws[WS_STAB + t * 9 + cnt++] =  (e + 1);
            if (senders[e]   == t) ws[WS_STAB + t * 9 + cnt++] = -(e + 1);
        }
        for (; cnt < 9; ++cnt) ws[WS_STAB + t * 9 + cnt] = 0;
    }
    // tanh table: entry i = bf16(tanh((i-2048) * ln2/256)), one-time.
    {
        unsigned short* tb = (unsigned short*)(ws + WS_TAB);
        for (int i = t; i < 4096; i += 128) {
            float xx = (float)(i - 2048) * 0.002707606174f;  // (ln2/2)/128
            tb[i] = (unsigned short)bf16_rne(tanhf(xx));
        }
    }
}

// r13 = r11 structure with HYBRID tanh (5 table + 3 exp per 8 pairs).
// r12 falsified occupancy-forcing; the per-CU LDS pipe is the saturated
// resource (gathers+conflicts = 2714cy/chunk-period = measured wall).
__global__ __launch_bounds__(BLOCK, 4) void
learn_forces_kernel(const float* __restrict__ D_V,
                    const float* __restrict__ b3,
                    const int* __restrict__ ws,
                    float* __restrict__ out, int ntime)
{
    __shared__ float einv[NP];
    __shared__ int   stab[NP * 9];            // signed edge list per planet: +-(e+1)
    __shared__ int   mpair[NE];               // packed bf16 (lo=lm_recv, hi=lm_send)
    __shared__ float secart[3][EPB];          // SoA cartesian edge forces (8.64 KB)
    __shared__ unsigned short ttab[4096];     // bf16 tanh table (8 KB)

    const int tid  = threadIdx.x;
    const int wv   = tid >> 6, lane = tid & 63;
    const int h    = lane >> 5;

    // ---- block-invariant constants: 9 coalesced int4 loads from ws ------
    short8 a1, a2a, a2b, a3a, a3b;
    f32x16 cb2, zf16;
    {
        const int4* wf = (const int4*)ws;
        *(int4*)&a1  = wf[0 * 64 + lane];
        *(int4*)&a2a = wf[1 * 64 + lane];
        *(int4*)&a2b = wf[2 * 64 + lane];
        *(int4*)&a3a = wf[3 * 64 + lane];
        *(int4*)&a3b = wf[4 * 64 + lane];
        int4* c4 = (int4*)&cb2;
        c4[0] = wf[5 * 64 + lane];
        c4[1] = wf[6 * 64 + lane];
        c4[2] = wf[7 * 64 + lane];
        c4[3] = wf[8 * 64 + lane];
    }
    #pragma unroll
    for (int r = 0; r < 16; ++r) zf16[r] = 0.0f;

    // table copy: 512 int4 (8 KB), 2 per thread; L2-resident source
    {
        const int4* s4 = (const int4*)(ws + WS_TAB);
        int4* d4 = (int4*)ttab;
        #pragma unroll
        for (int i = 0; i < 2; ++i) d4[tid + i * BLOCK] = s4[tid + i * BLOCK];
    }

    if (tid < NP)     einv[tid]  = ((const float*)ws)[WS_EINV + tid];
    if (tid < NE)     mpair[tid] = ws[WS_MPAIR + tid];
    if (tid < NP * 9) stab[tid]  = ws[WS_STAB + tid];
    const float b30 = b3[0], b31 = b3[1], b32 = b3[2];

    const int idxg1 = ((lane & 31) | 32) * 4;  // group-1 source lane (32+n)
    __syncthreads();

    // software prefetch of first chunk's D_V; running pointer avoids 64-bit
    // index mul per chunk.
    const long ebase = (long)blockIdx.x * EPB;
    const int  e0i   = wv * 64 + lane;
    const float* dvp = D_V + (ebase + e0i) * 3;   // points at e_loc of chunk c
    int le = e0i % NE;                            // own local-edge id (mod 45)
    float xn = 1.f, yn = 0.f, zn = 0.f;
    if (e0i < EPB) { xn = dvp[0]; yn = dvp[1]; zn = dvp[2]; }

    for (int c = wv; c < NCHUNK; c += 4) {
        const int  e_loc  = c * 64 + lane;
        const bool active = e_loc < EPB;

        float x = xn, y = yn, z = zn;
        // prefetch next chunk (e_loc advances by 256; EPB<=NCHUNK*64 so the
        // single bound check suffices)
        dvp += 256 * 3;
        xn = 1.f; yn = 0.f; zn = 0.f;
        if (e_loc + 256 < EPB) { xn = dvp[0]; yn = dvp[1]; zn = dvp[2]; }

        // ---- own-edge features ------------------------------------------
        float ss  = fmaf(x, x, fmaf(y, y, z * z));
        float rsq = __builtin_amdgcn_rsqf(ss);
        float r   = ss * rsq;
        float zr  = fminf(1.0f, fmaxf(-1.0f, z * rsq));
        float th  = acos_fast(zr);
        float ph  = atan2_fast(y, x);

        int mp   = mpair[le];                              // lo=lmr, hi=lms
        le += 256 % NE;                                    // advance: (le+31)%45
        le  = (le >= NE) ? le - NE : le;
        int p_rt = bf16pk2(r, th);                         // k0,k1
        int p_pm = (int)__builtin_amdgcn_perm(             // lo=ph (k2), hi=lmr (k3)
                       (unsigned)mp, __float_as_uint(ph) + 0x8000u, 0x05040302u);
        int p_s1 = (int)(((unsigned)mp >> 16) | 0x3F800000u); // k4=lms, k5=1.0 (bias)

        // ---- group-1 transport: 3 bperms (group 0 is lane-local) --------
        int q_rt = bperm_i(idxg1, p_rt);
        int q_pm = bperm_i(idxg1, p_pm);
        int q_s1 = bperm_i(idxg1, p_s1);

        // B-frags: h=1 lanes carry garbage at k=8..15 — masked by A1==0 there
        short8 bf0, bf1;
        { int* b = (int*)&bf0; b[0] = p_rt; b[1] = p_pm; b[2] = p_s1; b[3] = 0; }
        { int* b = (int*)&bf1; b[0] = q_rt; b[1] = q_pm; b[2] = q_s1; b[3] = 0; }

        // ---- group A: full MLP, ONE f32x16 acc live ---------------------
        float eA0, eA1, eA2;
        {
            short8 h0, h1;
            f32x16 acc = MFMA32(a1, bf0, zf16);
            tanh16_hyb(ttab, acc, h0, h1);
            acc = MFMA32(a2a, h0, cb2);
            acc = MFMA32(a2b, h1, acc);
            tanh16_hyb(ttab, acc, h0, h1);
            acc = MFMA32(a3a, h0, zf16);
            acc = MFMA32(a3b, h1, acc);
            eA0 = acc[0]; eA1 = acc[1]; eA2 = acc[2];
        }
        // keep scheduler from re-interleaving A and B (would re-inflate
        // the unified reg footprint back to 2+ live f32x16 chains)
        __builtin_amdgcn_sched_barrier(0);

        // ---- group B: full MLP, ONE f32x16 acc live ---------------------
        float eB0, eB1, eB2;
        {
            short8 h0, h1;
            f32x16 acc = MFMA32(a1, bf1, zf16);
            tanh16_hyb(ttab, acc, h0, h1);
            acc = MFMA32(a2a, h0, cb2);
            acc = MFMA32(a2b, h1, acc);
            tanh16_hyb(ttab, acc, h0, h1);
            acc = MFMA32(a3a, h0, zf16);
            acc = MFMA32(a3b, h1, acc);
            eB0 = acc[0]; eB1 = acc[1]; eB2 = acc[2];
        }

        // ---- own edge = group h, column n: regs 0..2 = (e0,e1,e2) -------
        float e0 = (h ? eB0 : eA0) + b30;
        float e1 = (h ? eB1 : eA1) + b31;
        float e2 = (h ? eB2 : eA2) + b32;

        // ---- sph -> cart, plain SoA LDS store ---------------------------
        float st = __sinf(e1), ct = __cosf(e1);
        float sp = __sinf(e2), cp = __cosf(e2);
        float am = e0 * st;
        f32x2 xy;
        {
            f32x2 cs; cs.x = cp; cs.y = sp;
            xy = cs * am;                      // v_pk_mul_f32
        }
        if (active) {
            secart[0][e_loc] = xy.x;
            secart[1][e_loc] = xy.y;
            secart[2][e_loc] = e0 * ct;
        }
    }
    __syncthreads();

    // ---- table-driven signed gather-sum: one (t, planet, comp) per thread
    const long t0g = (long)blockIdx.x * TS;
    for (int i = tid; i < TS * NP * 3; i += BLOCK) {
        int t  = i / (NP * 3);
        int pc = i - t * (NP * 3);
        int p  = pc / 3;
        int cc = pc - p * 3;
        const float* row = &secart[cc][t * NE];
        float s = 0.0f;
        #pragma unroll
        for (int j = 0; j < 9; ++j) {
            int es = stab[p * 9 + j];
            int e  = (es < 0 ? -es : es) - 1;
            float v = row[e];
            s += (es > 0) ? v : -v;
        }
        out[t0g * NP * 3 + i] = s * einv[p];   // contiguous 480-float range
    }
}

extern "C" void kernel_launch(void* const* d_in, const int* in_sizes, int n_in,
                              void* d_out, int out_size, void* d_ws, size_t ws_size,
                              hipStream_t stream) {
    const float* D_V  = (const float*)d_in[0];
    const float* logm = (const float*)d_in[1];
    const float* W1   = (const float*)d_in[2];
    const float* b1   = (const float*)d_in[3];
    const float* W2   = (const float*)d_in[4];
    const float* b2   = (const float*)d_in[5];
    const float* W3   = (const float*)d_in[6];
    const float* b3   = (const float*)d_in[7];
    const int* senders   = (const int*)d_in[8];
    const int* receivers = (const int*)d_in[9];

    int nedges = in_sizes[8];               // 45
    int ntime  = in_sizes[0] / 3 / nedges;  // 100000

    int* ws = (int*)d_ws;                   // needs ~18 KB

    prep_kernel<<<1, 128, 0, stream>>>(logm, W1, b1, W2, b2, W3,
                                       senders, receivers, ws);

    int nblocks = (ntime + TS - 1) / TS;    // 6250
    learn_forces_kernel<<<nblocks, BLOCK, 0, stream>>>(
        D_V, b3, ws, (float*)d_out, ntime);
}